// Round 15
// baseline (343.280 us; speedup 1.0000x reference)
//
#include <hip/hip_runtime.h>
#include <stdint.h>

#define BB 256
#define TT 2048
#define KK 64
#define CHUNK 64
#define NCHUNK (TT / CHUNK)   // 32
#define WARM 32
#define NSEG 16
#define SEGLEN (TT / NSEG)    // 128

__device__ __forceinline__ unsigned umax3(unsigned a, unsigned b, unsigned c) {
    return max(max(a, b), c);   // v_max3_u32
}

// LDS-only barrier: never drains vmcnt (bp stores / feat prefetch stay in flight)
__device__ __forceinline__ void lds_barrier() {
    asm volatile("s_waitcnt lgkmcnt(0)\n\ts_barrier" ::: "memory");
}

// ============================ kernel 1: forward ============================
// grid 4096 x 128 threads: block = (batch b = idx>>4, segment s = idx&15).
// 2 waves; lane l of BOTH waves owns tag-row l (fv replicated per wave).
// Wave w covers predecessors p in [32w, 32w+32): 32 v_readlane (fv broadcast,
// VALU pipe) + 32 v_add of pre-baked fixed-point keys
//   trk[i] = (round(clamp(tr,-256)*2048) << 6) | (63 - p)
// so one u32 max = max AND first-argmax. Cross-wave merge = 4B/lane via LDS
// (1 KB/step/block vs 16KB in the R13 design -> LDS pipe no longer binds).
__global__ __launch_bounds__(128, 8)
void viterbi_fwd_pm(const float* __restrict__ feats,
                    const float* __restrict__ trans,
                    const int* __restrict__ start_tag_p,
                    const int* __restrict__ stop_tag_p,
                    float* __restrict__ out,
                    unsigned char* __restrict__ bp_ws)
{
    const int bid  = blockIdx.x;
    const int b    = bid >> 4;
    const int s    = bid & 15;
    const int t0   = s * SEGLEN - (s ? WARM : 0);
    const int warmN = s ? WARM : 0;
    const int L    = warmN + SEGLEN;          // 128 or 160
    const int tid  = threadIdx.x;
    const int lane = tid & 63;
    const int w    = __builtin_amdgcn_readfirstlane(tid >> 6);  // 0..1
    const int pb   = w * 32;                  // this wave's p-base (SGPR)

    const int start_tag = *start_tag_p;
    const int stop_tag  = *stop_tag_p;

    __shared__ int part[2][2][KK];            // [buf][wave][row] partial keys (1KB)

    const float* fb = feats + (size_t)b * TT * KK + (size_t)t0 * KK + lane;
    unsigned char* bpb = bp_ws + (size_t)b * TT * KK;

    // pre-bake this wave's 32-wide transition slice for row `lane`
    int trk[32];
#pragma unroll
    for (int i = 0; i < 32; ++i) {
        const float tv = fmaxf(trans[lane * KK + pb + i], -256.0f);  // soft -inf
        trk[i] = (((int)rintf(tv * 2048.0f)) << 6) | (63 - (pb + i));
        asm volatile("" : "+v"(trk[i]));      // pin: forbid remat/reload in loop
    }

    // fv init (positive domain, fixed-point (value*2048)<<6)
    int fv = ((s || lane == start_tag) ? (2048 * 2048) : (512 * 2048)) << 6;

    // feat prefetch ring (depth 4), coalesced 256B/wave
    float r0 = fb[0 * KK], r1 = fb[1 * KK], r2 = fb[2 * KK], r3 = fb[3 * KK];

    auto stepf = [&](int tau, float featval, bool st) {
        const int fvb = fv;
        unsigned a0 = 0u, a1 = 0u, a2 = 0u, a3 = 0u;
#pragma unroll
        for (int i = 0; i < 32; i += 2) {
            const int spA = __builtin_amdgcn_readlane(fvb, pb + i);
            const int spB = __builtin_amdgcn_readlane(fvb, pb + i + 1);
            const unsigned cA = (unsigned)(spA + trk[i]);
            const unsigned cB = (unsigned)(spB + trk[i + 1]);
            switch ((i >> 1) & 3) {
                case 0: a0 = umax3(a0, cA, cB); break;
                case 1: a1 = umax3(a1, cA, cB); break;
                case 2: a2 = umax3(a2, cA, cB); break;
                case 3: a3 = umax3(a3, cA, cB); break;
            }
        }
        const unsigned kl = umax3(max(a0, a1), a2, a3);

        part[tau & 1][w][lane] = kl;          // 4B/lane, conflict-free
        lds_barrier();
        const unsigned K = max(kl, (unsigned)part[tau & 1][w ^ 1][lane]);

        if (st && w == 0)
            bpb[(size_t)(t0 + tau) * KK + lane] = (unsigned char)(63 - (K & 63u));

        fv = (int)(K & 0xFFFFFFC0u) + (((int)rintf(featval * 2048.0f)) << 6);
    };

    // warm steps (no bp stores); warmN is 0 or 32, multiple of 4
    for (int tau = 0; tau < warmN; tau += 4) {
        float n0 = fb[(tau + 4) * KK]; stepf(tau + 0, r0, false); r0 = n0;
        float n1 = fb[(tau + 5) * KK]; stepf(tau + 1, r1, false); r1 = n1;
        float n2 = fb[(tau + 6) * KK]; stepf(tau + 2, r2, false); r2 = n2;
        float n3 = fb[(tau + 7) * KK]; stepf(tau + 3, r3, false); r3 = n3;
    }
    // owned steps (bp stores)
    for (int tau = warmN; tau < L; tau += 4) {
        float n0 = fb[min(tau + 4, L - 1) * KK]; stepf(tau + 0, r0, true); r0 = n0;
        float n1 = fb[min(tau + 5, L - 1) * KK]; stepf(tau + 1, r1, true); r1 = n1;
        float n2 = fb[min(tau + 6, L - 1) * KK]; stepf(tau + 2, r2, true); r2 = n2;
        float n3 = fb[min(tau + 7, L - 1) * KK]; stepf(tau + 3, r3, true); r3 = n3;
    }

    // terminal argmax (last segment): uniform warm offset cancels in argmax;
    // true score recomputed from the decoded path in kernel 2.
    if (s == NSEG - 1 && w == 0) {
        const float fvf = (float)(fv >> 6) * (1.0f / 2048.0f);
        float bv = fvf + trans[stop_tag * KK + lane];
        int bi = lane;
#pragma unroll
        for (int off = 1; off < 64; off <<= 1) {
            const float ov = __shfl_xor(bv, off);
            const int   oi = __shfl_xor(bi, off);
            const bool take = (ov > bv) || (ov == bv && oi < bi);
            bv = take ? ov : bv;
            bi = take ? oi : bi;
        }
        if (lane == 0) out[b] = (float)bi;   // carrier for bestlast -> k2
    }
}

// ====================== kernel 2: backtrace + score ======================
__global__ __launch_bounds__(512)
void viterbi_bt_score(const float* __restrict__ feats,
                      const float* __restrict__ trans,
                      const int* __restrict__ start_tag_p,
                      const int* __restrict__ stop_tag_p,
                      float* __restrict__ out,
                      const unsigned char* __restrict__ bp_ws)
{
    const int b    = blockIdx.x;
    const int tid  = threadIdx.x;
    const int lane = tid & 63;
    const int w    = __builtin_amdgcn_readfirstlane(tid >> 6);  // 0..7

    __shared__ int cmap[NCHUNK][KK];
    __shared__ int be_lds[NCHUNK];
    __shared__ unsigned char path_lds[TT];
    __shared__ float red_lds[8];

    const unsigned char* bpb = bp_ws + (size_t)b * TT * KK;

    // ---- chunk-map composition: wave w composes chunks 4w..4w+3 ----
    {
        const int c0 = w * 4;
        const unsigned char* q0 = bpb + (size_t)(c0 + 0) * CHUNK * KK + lane;
        const unsigned char* q1 = bpb + (size_t)(c0 + 1) * CHUNK * KK + lane;
        const unsigned char* q2 = bpb + (size_t)(c0 + 2) * CHUNK * KK + lane;
        const unsigned char* q3 = bpb + (size_t)(c0 + 3) * CHUNK * KK + lane;
        int M0 = lane, M1 = lane, M2 = lane, M3 = lane;
        int a0 = q0[0], a1 = q1[0], a2 = q2[0], a3 = q3[0];
        int b0 = q0[KK], b1 = q1[KK], b2 = q2[KK], b3 = q3[KK];
        for (int t = 0; t < CHUNK; t += 2) {
            int n0 = 0, n1 = 0, n2 = 0, n3 = 0, m0 = 0, m1 = 0, m2 = 0, m3 = 0;
            if (t + 2 < CHUNK) {
                n0 = q0[(t + 2) * KK]; n1 = q1[(t + 2) * KK];
                n2 = q2[(t + 2) * KK]; n3 = q3[(t + 2) * KK];
                m0 = q0[(t + 3) * KK]; m1 = q1[(t + 3) * KK];
                m2 = q2[(t + 3) * KK]; m3 = q3[(t + 3) * KK];
            }
            M0 = __shfl(M0, a0); M1 = __shfl(M1, a1);
            M2 = __shfl(M2, a2); M3 = __shfl(M3, a3);
            M0 = __shfl(M0, b0); M1 = __shfl(M1, b1);
            M2 = __shfl(M2, b2); M3 = __shfl(M3, b3);
            a0 = n0; a1 = n1; a2 = n2; a3 = n3;
            b0 = m0; b1 = m1; b2 = m2; b3 = m3;
        }
        cmap[c0 + 0][lane] = M0; cmap[c0 + 1][lane] = M1;
        cmap[c0 + 2][lane] = M2; cmap[c0 + 3][lane] = M3;
    }
    __syncthreads();

    // ---- chunk-boundary tags (serial, 32 LDS hops) ----
    if (tid == 0) {
        int x = (int)out[b];          // bestlast from k1
        be_lds[NCHUNK - 1] = x;
        for (int c = NCHUNK - 1; c >= 1; --c) {
            x = cmap[c][x];
            be_lds[c - 1] = x;
        }
    }
    __syncthreads();

    // ---- parallel interior backtrace (32 chunks), also fill path_lds ----
    if (tid < NCHUNK) {
        const int c = tid;
        int x = be_lds[c];
        float* po = out + BB + (size_t)b * TT;
        for (int t = (c + 1) * CHUNK - 1; t >= c * CHUNK; --t) {
            po[t] = (float)x;
            path_lds[t] = (unsigned char)x;
            x = (int)bpb[(size_t)t * KK + x];
        }
    }
    __syncthreads();

    // ---- exact score recompute along the decoded path ----
    const float* fbb = feats + (size_t)b * TT * KK;
    const int start_tag = *start_tag_p;
    const int stop_tag  = *stop_tag_p;
    float acc = 0.0f;
    for (int t = tid; t < TT; t += 512) {
        const int xt = path_lds[t];
        const int xp = (t > 0) ? (int)path_lds[t - 1] : start_tag;
        acc += fbb[(size_t)t * KK + xt] + trans[xt * KK + xp];
    }
    if (tid == 0) acc += trans[stop_tag * KK + (int)path_lds[TT - 1]];
#pragma unroll
    for (int off = 1; off < 64; off <<= 1) acc += __shfl_xor(acc, off);
    if (lane == 0) red_lds[w] = acc;
    __syncthreads();
    if (tid == 0) {
        float sc = 0.0f;
        for (int i = 0; i < 8; ++i) sc += red_lds[i];
        out[b] = sc;
    }
}

extern "C" void kernel_launch(void* const* d_in, const int* in_sizes, int n_in,
                              void* d_out, int out_size, void* d_ws, size_t ws_size,
                              hipStream_t stream) {
    const float* feats = (const float*)d_in[0];
    const float* trans = (const float*)d_in[1];
    const int* start_tag = (const int*)d_in[2];
    const int* stop_tag  = (const int*)d_in[3];
    float* out = (float*)d_out;
    unsigned char* bp = (unsigned char*)d_ws;   // B*T*K = 33.5 MB backpointers

    viterbi_fwd_pm<<<BB * NSEG, 128, 0, stream>>>(feats, trans, start_tag, stop_tag, out, bp);
    viterbi_bt_score<<<BB, 512, 0, stream>>>(feats, trans, start_tag, stop_tag, out, bp);
}

// Round 16
// 322.300 us; speedup vs baseline: 1.0651x; 1.0651x over previous
//
#include <hip/hip_runtime.h>
#include <stdint.h>

#define BB 256
#define TT 2048
#define KK 64
#define CHUNK 64
#define NCHUNK (TT / CHUNK)   // 32
#define WARM 32
#define NSEG 16
#define SEGLEN (TT / NSEG)    // 128

typedef float f32x4 __attribute__((ext_vector_type(4)));

__device__ __forceinline__ unsigned umax3(unsigned a, unsigned b, unsigned c) {
    return max(max(a, b), c);   // v_max3_u32
}

// LDS-only barrier: never drains vmcnt (bp stores / feat prefetch stay in flight)
__device__ __forceinline__ void lds_barrier() {
    asm volatile("s_waitcnt lgkmcnt(0)\n\ts_barrier" ::: "memory");
}

// ============================ kernel 1: forward ============================
// grid 4096 x 128 threads: block = (batch b = idx>>4, segment s = idx&15).
// 2 waves; lane l of BOTH waves owns tag-row l (fv replicated per wave).
// Wave w covers predecessors p in [32w, 32w+32): 32 v_readlane (fv broadcast,
// VALU pipe) + 32 v_add of pre-baked fixed-point keys
//   trk[i] = (round(clamp(tr,-256)*2048) << 6) | (63 - p)
// -> one u32 max = max AND first-argmax. Cross-wave merge = 4B/lane via LDS.
// trk source values are loaded via VOLATILE inline-asm global_load_dwordx4 so
// the register allocator CANNOT rematerialize them per step (R14/R15 failure).
__global__ __launch_bounds__(128, 8)
void viterbi_fwd_pm(const float* __restrict__ feats,
                    const float* __restrict__ trans,
                    const int* __restrict__ start_tag_p,
                    const int* __restrict__ stop_tag_p,
                    float* __restrict__ out,
                    unsigned char* __restrict__ bp_ws)
{
    const int bid  = blockIdx.x;
    const int b    = bid >> 4;
    const int s    = bid & 15;
    const int t0   = s * SEGLEN - (s ? WARM : 0);
    const int warmN = s ? WARM : 0;
    const int L    = warmN + SEGLEN;          // 128 or 160
    const int tid  = threadIdx.x;
    const int lane = tid & 63;
    const int w    = __builtin_amdgcn_readfirstlane(tid >> 6);  // 0..1
    const int pb   = w * 32;                  // this wave's p-base (SGPR)

    const int start_tag = *start_tag_p;
    const int stop_tag  = *stop_tag_p;

    __shared__ int part[2][2][KK];            // [buf][wave][row] partial keys (1KB)

    const float* fb = feats + (size_t)b * TT * KK + (size_t)t0 * KK + lane;
    unsigned char* bpb = bp_ws + (size_t)b * TT * KK;

    // ---- load transition slice via volatile asm (non-rematerializable) ----
    f32x4 tv[8];
    {
        const float* ap = &trans[lane * KK + pb];
#pragma unroll
        for (int q = 0; q < 8; ++q)
            asm volatile("global_load_dwordx4 %0, %1, off"
                         : "=v"(tv[q]) : "v"(ap + q * 4));
        asm volatile("s_waitcnt vmcnt(0)" ::: "memory");
    }
    // bake packed fixed-point keys (kept in VGPRs: sources are asm outputs)
    int trk[32];
#pragma unroll
    for (int q = 0; q < 8; ++q) {
#pragma unroll
        for (int e = 0; e < 4; ++e) {
            const int i = q * 4 + e;
            const float c = fmaxf(tv[q][e], -256.0f);            // soft -inf
            trk[i] = (((int)rintf(c * 2048.0f)) << 6) | (63 - (pb + i));
        }
    }

    // fv init (positive domain, fixed-point (value*2048)<<6)
    int fv = ((s || lane == start_tag) ? (2048 * 2048) : (512 * 2048)) << 6;

    // feat prefetch ring (depth 4), coalesced 256B/wave
    float r0 = fb[0 * KK], r1 = fb[1 * KK], r2 = fb[2 * KK], r3 = fb[3 * KK];

    auto stepf = [&](int tau, float featval, bool st) {
        const int fvb = fv;
        unsigned a0 = 0u, a1 = 0u, a2 = 0u, a3 = 0u;
#pragma unroll
        for (int i = 0; i < 32; i += 4) {
            const int s0 = __builtin_amdgcn_readlane(fvb, pb + i + 0);
            const int s1 = __builtin_amdgcn_readlane(fvb, pb + i + 1);
            const int s2 = __builtin_amdgcn_readlane(fvb, pb + i + 2);
            const int s3 = __builtin_amdgcn_readlane(fvb, pb + i + 3);
            const unsigned c0 = (unsigned)(s0 + trk[i + 0]);
            const unsigned c1 = (unsigned)(s1 + trk[i + 1]);
            const unsigned c2 = (unsigned)(s2 + trk[i + 2]);
            const unsigned c3 = (unsigned)(s3 + trk[i + 3]);
            a0 = umax3(a0, c0, c1);
            a1 = umax3(a1, c2, c3);
            // rotate accumulator roles to deepen ILP
            const unsigned t = a0; a0 = a2; a2 = t;
            const unsigned u = a1; a1 = a3; a3 = u;
        }
        const unsigned kl = umax3(max(a0, a1), a2, a3);

        part[tau & 1][w][lane] = kl;          // 4B/lane, conflict-free
        lds_barrier();
        const unsigned K = max(kl, (unsigned)part[tau & 1][w ^ 1][lane]);

        if (st && w == 0)
            bpb[(size_t)(t0 + tau) * KK + lane] = (unsigned char)(63 - (K & 63u));

        fv = (int)(K & 0xFFFFFFC0u) + (((int)rintf(featval * 2048.0f)) << 6);
    };

    // warm steps (no bp stores); warmN is 0 or 32, multiple of 4
    for (int tau = 0; tau < warmN; tau += 4) {
        float n0 = fb[(tau + 4) * KK]; stepf(tau + 0, r0, false); r0 = n0;
        float n1 = fb[(tau + 5) * KK]; stepf(tau + 1, r1, false); r1 = n1;
        float n2 = fb[(tau + 6) * KK]; stepf(tau + 2, r2, false); r2 = n2;
        float n3 = fb[(tau + 7) * KK]; stepf(tau + 3, r3, false); r3 = n3;
    }
    // owned steps (bp stores)
    for (int tau = warmN; tau < L; tau += 4) {
        float n0 = fb[min(tau + 4, L - 1) * KK]; stepf(tau + 0, r0, true); r0 = n0;
        float n1 = fb[min(tau + 5, L - 1) * KK]; stepf(tau + 1, r1, true); r1 = n1;
        float n2 = fb[min(tau + 6, L - 1) * KK]; stepf(tau + 2, r2, true); r2 = n2;
        float n3 = fb[min(tau + 7, L - 1) * KK]; stepf(tau + 3, r3, true); r3 = n3;
    }

    // terminal argmax (last segment): uniform warm offset cancels in argmax;
    // true score recomputed from the decoded path in kernel 2.
    if (s == NSEG - 1 && w == 0) {
        const float fvf = (float)(fv >> 6) * (1.0f / 2048.0f);
        float bv = fvf + trans[stop_tag * KK + lane];
        int bi = lane;
#pragma unroll
        for (int off = 1; off < 64; off <<= 1) {
            const float ov = __shfl_xor(bv, off);
            const int   oi = __shfl_xor(bi, off);
            const bool take = (ov > bv) || (ov == bv && oi < bi);
            bv = take ? ov : bv;
            bi = take ? oi : bi;
        }
        if (lane == 0) out[b] = (float)bi;   // carrier for bestlast -> k2
    }
}

// ====================== kernel 2: backtrace + score ======================
__global__ __launch_bounds__(512)
void viterbi_bt_score(const float* __restrict__ feats,
                      const float* __restrict__ trans,
                      const int* __restrict__ start_tag_p,
                      const int* __restrict__ stop_tag_p,
                      float* __restrict__ out,
                      const unsigned char* __restrict__ bp_ws)
{
    const int b    = blockIdx.x;
    const int tid  = threadIdx.x;
    const int lane = tid & 63;
    const int w    = __builtin_amdgcn_readfirstlane(tid >> 6);  // 0..7

    __shared__ int cmap[NCHUNK][KK];
    __shared__ int be_lds[NCHUNK];
    __shared__ unsigned char path_lds[TT];
    __shared__ float red_lds[8];

    const unsigned char* bpb = bp_ws + (size_t)b * TT * KK;

    // ---- chunk-map composition: wave w composes chunks 4w..4w+3 ----
    {
        const int c0 = w * 4;
        const unsigned char* q0 = bpb + (size_t)(c0 + 0) * CHUNK * KK + lane;
        const unsigned char* q1 = bpb + (size_t)(c0 + 1) * CHUNK * KK + lane;
        const unsigned char* q2 = bpb + (size_t)(c0 + 2) * CHUNK * KK + lane;
        const unsigned char* q3 = bpb + (size_t)(c0 + 3) * CHUNK * KK + lane;
        int M0 = lane, M1 = lane, M2 = lane, M3 = lane;
        int a0 = q0[0], a1 = q1[0], a2 = q2[0], a3 = q3[0];
        int b0 = q0[KK], b1 = q1[KK], b2 = q2[KK], b3 = q3[KK];
        for (int t = 0; t < CHUNK; t += 2) {
            int n0 = 0, n1 = 0, n2 = 0, n3 = 0, m0 = 0, m1 = 0, m2 = 0, m3 = 0;
            if (t + 2 < CHUNK) {
                n0 = q0[(t + 2) * KK]; n1 = q1[(t + 2) * KK];
                n2 = q2[(t + 2) * KK]; n3 = q3[(t + 2) * KK];
                m0 = q0[(t + 3) * KK]; m1 = q1[(t + 3) * KK];
                m2 = q2[(t + 3) * KK]; m3 = q3[(t + 3) * KK];
            }
            M0 = __shfl(M0, a0); M1 = __shfl(M1, a1);
            M2 = __shfl(M2, a2); M3 = __shfl(M3, a3);
            M0 = __shfl(M0, b0); M1 = __shfl(M1, b1);
            M2 = __shfl(M2, b2); M3 = __shfl(M3, b3);
            a0 = n0; a1 = n1; a2 = n2; a3 = n3;
            b0 = m0; b1 = m1; b2 = m2; b3 = m3;
        }
        cmap[c0 + 0][lane] = M0; cmap[c0 + 1][lane] = M1;
        cmap[c0 + 2][lane] = M2; cmap[c0 + 3][lane] = M3;
    }
    __syncthreads();

    // ---- chunk-boundary tags (serial, 32 LDS hops) ----
    if (tid == 0) {
        int x = (int)out[b];          // bestlast from k1
        be_lds[NCHUNK - 1] = x;
        for (int c = NCHUNK - 1; c >= 1; --c) {
            x = cmap[c][x];
            be_lds[c - 1] = x;
        }
    }
    __syncthreads();

    // ---- parallel interior backtrace (32 chunks), also fill path_lds ----
    if (tid < NCHUNK) {
        const int c = tid;
        int x = be_lds[c];
        float* po = out + BB + (size_t)b * TT;
        for (int t = (c + 1) * CHUNK - 1; t >= c * CHUNK; --t) {
            po[t] = (float)x;
            path_lds[t] = (unsigned char)x;
            x = (int)bpb[(size_t)t * KK + x];
        }
    }
    __syncthreads();

    // ---- exact score recompute along the decoded path ----
    const float* fbb = feats + (size_t)b * TT * KK;
    const int start_tag = *start_tag_p;
    const int stop_tag  = *stop_tag_p;
    float acc = 0.0f;
    for (int t = tid; t < TT; t += 512) {
        const int xt = path_lds[t];
        const int xp = (t > 0) ? (int)path_lds[t - 1] : start_tag;
        acc += fbb[(size_t)t * KK + xt] + trans[xt * KK + xp];
    }
    if (tid == 0) acc += trans[stop_tag * KK + (int)path_lds[TT - 1]];
#pragma unroll
    for (int off = 1; off < 64; off <<= 1) acc += __shfl_xor(acc, off);
    if (lane == 0) red_lds[w] = acc;
    __syncthreads();
    if (tid == 0) {
        float sc = 0.0f;
        for (int i = 0; i < 8; ++i) sc += red_lds[i];
        out[b] = sc;
    }
}

extern "C" void kernel_launch(void* const* d_in, const int* in_sizes, int n_in,
                              void* d_out, int out_size, void* d_ws, size_t ws_size,
                              hipStream_t stream) {
    const float* feats = (const float*)d_in[0];
    const float* trans = (const float*)d_in[1];
    const int* start_tag = (const int*)d_in[2];
    const int* stop_tag  = (const int*)d_in[3];
    float* out = (float*)d_out;
    unsigned char* bp = (unsigned char*)d_ws;   // B*T*K = 33.5 MB backpointers

    viterbi_fwd_pm<<<BB * NSEG, 128, 0, stream>>>(feats, trans, start_tag, stop_tag, out, bp);
    viterbi_bt_score<<<BB, 512, 0, stream>>>(feats, trans, start_tag, stop_tag, out, bp);
}